// Round 1
// baseline (5181.722 us; speedup 1.0000x reference)
//
#include <hip/hip_runtime.h>
#include <hip/hip_bf16.h>
#include <stdint.h>

#define NWIN 4096
#define NTOK 49
#define CDIM 192
#define NH   6
#define HD   32
#define NT   256

constexpr int QS = 36;   // q/k/v LDS row stride (floats), padded to spread banks
constexpr int SS = 52;   // score LDS row stride (floats), mult of 4 for float4 reads

__global__ __launch_bounds__(NT)
void wmsa_fused(const float* __restrict__ x,
                const float* __restrict__ qkv_w,
                const float* __restrict__ qkv_b,
                const float* __restrict__ proj_w,
                const float* __restrict__ proj_b,
                const float* __restrict__ rpe_table,
                const int*   __restrict__ rpe_idx,
                float* __restrict__ out)
{
    __shared__ float qkvs[3 * NTOK * QS];                    // 21168 B: q(scaled),k,v for one head
    __shared__ float sc[NTOK * SS];                          // 10192 B: scores -> probs
    __shared__ alignas(16) unsigned short ao[NTOK * CDIM];   // 18816 B: attn out, bf16 bits
    // total 50176 B -> 3 blocks/CU by LDS

    const int b  = blockIdx.x;
    const int t  = threadIdx.x;
    const int tj = t & 15;    // 16 column-groups of 6
    const int tn = t >> 4;    // 16 row-groups, rows tn+16*i
    const float scale = 0.17677669529663687f; // 32^-0.5

    const float* xb = x + (size_t)b * (NTOK * CDIM);

    for (int h = 0; h < NH; ++h) {
        // ---------------- qkv projection for head h: [49x192] @ [96x192]^T ----------------
        float acc[4][6];
        #pragma unroll
        for (int i = 0; i < 4; ++i) {
            #pragma unroll
            for (int jj = 0; jj < 6; ++jj) acc[i][jj] = 0.f;
        }

        int jrow[6]; // rows of qkv_w this thread needs: j = s*192 + h*32 + d
        #pragma unroll
        for (int jj = 0; jj < 6; ++jj) {
            int e = tj * 6 + jj;          // 0..95  (s = e/32 in {q,k,v}, d = e%32)
            int s = e >> 5, d = e & 31;
            jrow[jj] = s * CDIM + h * HD + d;
        }

        for (int k = 0; k < CDIM; k += 4) {
            float4 w4[6];
            #pragma unroll
            for (int jj = 0; jj < 6; ++jj)
                w4[jj] = *(const float4*)(qkv_w + (size_t)jrow[jj] * CDIM + k);
            #pragma unroll
            for (int i = 0; i < 4; ++i) {
                int n = tn + 16 * i;
                if (n < NTOK) {
                    float4 x4 = *(const float4*)(xb + n * CDIM + k);
                    #pragma unroll
                    for (int jj = 0; jj < 6; ++jj)
                        acc[i][jj] += x4.x * w4[jj].x + x4.y * w4[jj].y
                                    + x4.z * w4[jj].z + x4.w * w4[jj].w;
                }
            }
        }

        #pragma unroll
        for (int jj = 0; jj < 6; ++jj) {
            int e = tj * 6 + jj;
            int s = e >> 5, d = e & 31;
            float bias = qkv_b[jrow[jj]];
            float mul = (s == 0) ? scale : 1.f;
            #pragma unroll
            for (int i = 0; i < 4; ++i) {
                int n = tn + 16 * i;
                if (n < NTOK)
                    qkvs[s * (NTOK * QS) + n * QS + d] = (acc[i][jj] + bias) * mul;
            }
        }
        __syncthreads();

        const float* qsh = qkvs;
        const float* ksh = qkvs + NTOK * QS;
        const float* vsh = qkvs + 2 * NTOK * QS;

        // ---------------- scores = q k^T + rpe bias ----------------
        for (int p = t; p < NTOK * NTOK; p += NT) {
            int n = p / NTOK, m = p - n * NTOK;   // p == n*49+m == rpe_idx flat index
            float s = 0.f;
            #pragma unroll
            for (int d = 0; d < HD; d += 4) {
                float4 q4 = *(const float4*)(qsh + n * QS + d);
                float4 k4 = *(const float4*)(ksh + m * QS + d);
                s += q4.x * k4.x + q4.y * k4.y + q4.z * k4.z + q4.w * k4.w;
            }
            s += rpe_table[rpe_idx[p] * NH + h];
            sc[n * SS + m] = s;
        }
        __syncthreads();

        // ---------------- softmax per row ----------------
        if (t < NTOK) {
            float mx = -1e30f;
            for (int m = 0; m < NTOK; ++m) mx = fmaxf(mx, sc[t * SS + m]);
            float sum = 0.f;
            for (int m = 0; m < NTOK; ++m) {
                float e = __expf(sc[t * SS + m] - mx);
                sc[t * SS + m] = e;
                sum += e;
            }
            float inv = 1.f / sum;
            for (int m = 0; m < NTOK; ++m) sc[t * SS + m] *= inv;
        }
        __syncthreads();

        // ---------------- out_h = P @ V, store bf16 into ao ----------------
        {
            int d = t & 31, nn = t >> 5;  // 32 d-lanes x 8 n-groups
            #pragma unroll
            for (int i = 0; i < 7; ++i) {
                int n = nn + 8 * i;
                if (n < NTOK) {
                    float o = 0.f;
                    for (int m = 0; m < 48; m += 4) {
                        float4 p4 = *(const float4*)(sc + n * SS + m);
                        o += p4.x * vsh[(m + 0) * QS + d];
                        o += p4.y * vsh[(m + 1) * QS + d];
                        o += p4.z * vsh[(m + 2) * QS + d];
                        o += p4.w * vsh[(m + 3) * QS + d];
                    }
                    o += sc[n * SS + 48] * vsh[48 * QS + d];
                    // round-to-nearest-even bf16
                    unsigned int bits = __float_as_uint(o);
                    bits += 0x7fffu + ((bits >> 16) & 1u);
                    ao[n * CDIM + h * HD + d] = (unsigned short)(bits >> 16);
                }
            }
        }
        __syncthreads();  // protects qkvs/sc for next head, ao for proj phase
    }

    // ---------------- output projection: [49x192] @ [192x192]^T + b ----------------
    for (int jp = 0; jp < 2; ++jp) {
        float acc[4][6];
        #pragma unroll
        for (int i = 0; i < 4; ++i) {
            #pragma unroll
            for (int jj = 0; jj < 6; ++jj) acc[i][jj] = 0.f;
        }
        const int jbase = jp * 96 + tj * 6;

        for (int k = 0; k < CDIM; k += 4) {
            float4 w4[6];
            #pragma unroll
            for (int jj = 0; jj < 6; ++jj)
                w4[jj] = *(const float4*)(proj_w + (size_t)(jbase + jj) * CDIM + k);
            #pragma unroll
            for (int i = 0; i < 4; ++i) {
                int n = tn + 16 * i;
                if (n < NTOK) {
                    uint2 u = *(const uint2*)(ao + n * CDIM + k);  // 4 bf16
                    float a0 = __uint_as_float(u.x << 16);
                    float a1 = __uint_as_float(u.x & 0xffff0000u);
                    float a2 = __uint_as_float(u.y << 16);
                    float a3 = __uint_as_float(u.y & 0xffff0000u);
                    #pragma unroll
                    for (int jj = 0; jj < 6; ++jj)
                        acc[i][jj] += a0 * w4[jj].x + a1 * w4[jj].y
                                    + a2 * w4[jj].z + a3 * w4[jj].w;
                }
            }
        }

        #pragma unroll
        for (int jj = 0; jj < 6; ++jj) {
            int j = jbase + jj;
            float pb = proj_b[j];
            #pragma unroll
            for (int i = 0; i < 4; ++i) {
                int n = tn + 16 * i;
                if (n < NTOK)
                    out[((size_t)b * NTOK + n) * CDIM + j] = acc[i][jj] + pb;
            }
        }
    }
}

extern "C" void kernel_launch(void* const* d_in, const int* in_sizes, int n_in,
                              void* d_out, int out_size, void* d_ws, size_t ws_size,
                              hipStream_t stream)
{
    const float* x      = (const float*)d_in[0];
    const float* qkv_w  = (const float*)d_in[1];
    const float* qkv_b  = (const float*)d_in[2];
    const float* proj_w = (const float*)d_in[3];
    const float* proj_b = (const float*)d_in[4];
    const float* rpe_t  = (const float*)d_in[5];
    const int*   rpe_i  = (const int*)d_in[6];
    float*       o      = (float*)d_out;

    wmsa_fused<<<dim3(NWIN), dim3(NT), 0, stream>>>(
        x, qkv_w, qkv_b, proj_w, proj_b, rpe_t, rpe_i, o);
}

// Round 2
// 593.567 us; speedup vs baseline: 8.7298x; 8.7298x over previous
//
#include <hip/hip_runtime.h>
#include <stdint.h>

#define NWIN 4096
#define NTOK 49
#define CDIM 192
#define NH   6
#define HD   32

typedef __attribute__((ext_vector_type(8))) short short8;
typedef __attribute__((ext_vector_type(4))) float floatx4;
typedef unsigned short ushort_t;
typedef unsigned int uint32;

// LDS row strides in bf16 elements: multiples of 8 (16-B alignment for b128),
// dword-stride mod 32 in {2,4,20} -> <=2-way bank aliasing (free per m136).
#define XS_S 200   // x-staging / attention-output rows (49 x 200)
#define QK_S 296   // per-pass qkv rows: 288 cols + 8 pad
#define P_S  72    // probability rows (cols 0..63 used, 49..63 zeroed)
#define VT_S 72    // V-transposed rows (cols 0..63 used, 49..63 zeroed)

__device__ __forceinline__ ushort_t f2bf(float f) {
    uint32 u = __float_as_uint(f);
    u += 0x7fffu + ((u >> 16) & 1u);   // round-to-nearest-even
    return (ushort_t)(u >> 16);
}

// Pre-convert weights to bf16 and pre-gather rpe bias into [6][49][64] fp32.
__global__ void wmsa_prologue(const float* __restrict__ qkv_w,
                              const float* __restrict__ proj_w,
                              const float* __restrict__ rpe_table,
                              const int*   __restrict__ rpe_idx,
                              ushort_t* __restrict__ qkv_wb,
                              ushort_t* __restrict__ proj_wb,
                              float* __restrict__ biasws)
{
    int i = blockIdx.x * 256 + threadIdx.x;
    if (i < 110592) {
        qkv_wb[i] = f2bf(qkv_w[i]);
    } else if (i < 147456) {
        proj_wb[i - 110592] = f2bf(proj_w[i - 110592]);
    } else if (i < 147456 + NH * NTOK * 64) {
        int r = i - 147456;
        int h = r / (NTOK * 64);
        int rem = r - h * (NTOK * 64);
        int n = rem >> 6, m = rem & 63;
        biasws[r] = (m < NTOK) ? rpe_table[rpe_idx[n * NTOK + m] * NH + h] : 0.f;
    }
}

__global__ __launch_bounds__(256)
void wmsa_mfma(const float* __restrict__ x,
               const ushort_t* __restrict__ qkv_wb,
               const float* __restrict__ qkv_b,
               const ushort_t* __restrict__ proj_wb,
               const float* __restrict__ proj_b,
               const float* __restrict__ biasws,
               float* __restrict__ out)
{
    // region0 holds x (bf16) during fragment preload, then attention output.
    __shared__ alignas(16) ushort_t reg0[NTOK * XS_S];   // 19600 B
    __shared__ alignas(16) ushort_t qkvs[NTOK * QK_S];   // 29008 B
    __shared__ alignas(16) ushort_t Pb[NTOK * P_S];      //  7056 B
    __shared__ alignas(16) ushort_t Vt[HD * VT_S];       //  4608 B  (total 60272 B)

    const int b    = blockIdx.x;
    const int t    = threadIdx.x;
    const int w    = t >> 6;      // wave 0..3
    const int lane = t & 63;
    const int quad = lane >> 4;   // MFMA k-group
    const int c    = lane & 15;   // MFMA row/col within group
    const float scale = 0.17677669529663687f;   // 32^-0.5

    const float* xb = x + (size_t)b * (NTOK * CDIM);

    // ---------- stage x -> bf16 LDS (coalesced float4) ----------
    for (int i = t; i < (NTOK * CDIM) / 4; i += 256) {
        int e = i * 4;
        int n = e / CDIM, d = e - n * CDIM;
        float4 v = *(const float4*)(xb + e);
        ushort_t* p = &reg0[n * XS_S + d];
        p[0] = f2bf(v.x); p[1] = f2bf(v.y); p[2] = f2bf(v.z); p[3] = f2bf(v.w);
    }
    __syncthreads();

    // ---------- preload all x A-fragments into registers (96 VGPRs) ----------
    // A layout (16x16x32): m = lane&15, k = quad*8 + j  [m120-verified]
    short8 afr[4][6];
    #pragma unroll
    for (int mt = 0; mt < 4; ++mt) {
        int row = mt * 16 + c;   // rows >=49 read garbage; confined to masked rows
        #pragma unroll
        for (int ks = 0; ks < 6; ++ks)
            afr[mt][ks] = *(const short8*)&reg0[row * XS_S + ks * 32 + quad * 8];
    }
    // no sync needed: first write to reg0 (attn out) is after >=2 barriers

    for (int pass = 0; pass < 2; ++pass) {
        // ---------- qkv GEMM for heads 3*pass..3*pass+2 : [49x192]@[192x288] ----------
        // N-tiles split across waves (no redundant weight reads).
        for (int nt = w; nt < 18; nt += 4) {
            int s_idx = nt / 6;                  // 0=q 1=k 2=v
            int rem   = nt - s_idx * 6;
            int hh    = rem >> 1;                // head within pass
            int half  = nt & 1;
            int jrow  = s_idx * CDIM + (3 * pass + hh) * HD + half * 16 + c;
            const ushort_t* bp = qkv_wb + jrow * CDIM + quad * 8;

            floatx4 z = {0.f, 0.f, 0.f, 0.f};
            floatx4 acc[4];
            #pragma unroll
            for (int mt = 0; mt < 4; ++mt) acc[mt] = z;

            #pragma unroll
            for (int ks = 0; ks < 6; ++ks) {
                short8 bf = *(const short8*)(bp + ks * 32);  // B: n=lane&15, k=quad*8+j
                #pragma unroll
                for (int mt = 0; mt < 4; ++mt)
                    acc[mt] = __builtin_amdgcn_mfma_f32_16x16x32_bf16(
                        afr[mt][ks], bf, acc[mt], 0, 0, 0);
            }

            float bias = qkv_b[jrow];
            float mul  = (s_idx == 0) ? scale : 1.f;
            int ecol   = s_idx * 96 + hh * HD + half * 16 + c;
            #pragma unroll
            for (int mt = 0; mt < 4; ++mt) {
                #pragma unroll
                for (int r = 0; r < 4; ++r) {
                    int n = mt * 16 + quad * 4 + r;   // C: col=lane&15, row=quad*4+reg
                    if (n < NTOK)
                        qkvs[n * QK_S + ecol] = f2bf((acc[mt][r] + bias) * mul);
                }
            }
        }
        __syncthreads();

        // ---------- attention, 3 heads ----------
        for (int hh = 0; hh < 3; ++hh) {
            int h = pass * 3 + hh;

            // scores: wave = M-tile (query rows w*16..w*16+15), K=32 = one mfma
            short8 aq = *(const short8*)&qkvs[(w * 16 + c) * QK_S + hh * HD + quad * 8];
            floatx4 sacc[4];
            #pragma unroll
            for (int nt = 0; nt < 4; ++nt) {
                short8 bk = *(const short8*)&qkvs[(nt * 16 + c) * QK_S + 96 + hh * HD + quad * 8];
                floatx4 z = {0.f, 0.f, 0.f, 0.f};
                sacc[nt] = __builtin_amdgcn_mfma_f32_16x16x32_bf16(aq, bk, z, 0, 0, 0);
            }

            // in-register softmax: row n = w*16 + quad*4 + r lives across the
            // 16 lanes of this quad -> shfl_xor 1/2/4/8 reduces it.
            const float* bpb = biasws + h * (NTOK * 64);
            #pragma unroll
            for (int r = 0; r < 4; ++r) {
                int n  = w * 16 + quad * 4 + r;
                int nc = (n < NTOK) ? n : (NTOK - 1);   // clamp for pad rows
                float sv[4];
                #pragma unroll
                for (int nt = 0; nt < 4; ++nt) {
                    int col = nt * 16 + c;
                    float bias = bpb[nc * 64 + col];
                    sv[nt] = (col < NTOK) ? (sacc[nt][r] + bias) : -1e30f;
                }
                float m0 = fmaxf(fmaxf(sv[0], sv[1]), fmaxf(sv[2], sv[3]));
                m0 = fmaxf(m0, __shfl_xor(m0, 1));
                m0 = fmaxf(m0, __shfl_xor(m0, 2));
                m0 = fmaxf(m0, __shfl_xor(m0, 4));
                m0 = fmaxf(m0, __shfl_xor(m0, 8));
                float ex[4], s0 = 0.f;
                #pragma unroll
                for (int nt = 0; nt < 4; ++nt) { ex[nt] = __expf(sv[nt] - m0); s0 += ex[nt]; }
                s0 += __shfl_xor(s0, 1);
                s0 += __shfl_xor(s0, 2);
                s0 += __shfl_xor(s0, 4);
                s0 += __shfl_xor(s0, 8);
                float inv = 1.f / s0;
                if (n < NTOK) {
                    #pragma unroll
                    for (int nt = 0; nt < 4; ++nt)   // cols 49..63 -> exact 0 (K-pad)
                        Pb[n * P_S + nt * 16 + c] = f2bf(ex[nt] * inv);
                }
            }

            // V^T staging with zero pad m=49..63
            for (int i = t; i < HD * 64; i += 256) {
                int d = i >> 6, m = i & 63;
                Vt[d * VT_S + m] = (m < NTOK)
                    ? qkvs[m * QK_S + 192 + hh * HD + d] : (ushort_t)0;
            }
            __syncthreads();

            // PV: [49x64(pad)] @ [64x32], 2 k-steps, wave = M-tile
            floatx4 z2 = {0.f, 0.f, 0.f, 0.f};
            floatx4 oacc[2]; oacc[0] = z2; oacc[1] = z2;
            #pragma unroll
            for (int ks = 0; ks < 2; ++ks) {
                short8 ap = *(const short8*)&Pb[(w * 16 + c) * P_S + ks * 32 + quad * 8];
                #pragma unroll
                for (int nt = 0; nt < 2; ++nt) {
                    short8 bv = *(const short8*)&Vt[(nt * 16 + c) * VT_S + ks * 32 + quad * 8];
                    oacc[nt] = __builtin_amdgcn_mfma_f32_16x16x32_bf16(ap, bv, oacc[nt], 0, 0, 0);
                }
            }
            #pragma unroll
            for (int nt = 0; nt < 2; ++nt) {
                #pragma unroll
                for (int r = 0; r < 4; ++r) {
                    int n = w * 16 + quad * 4 + r;
                    if (n < NTOK)
                        reg0[n * XS_S + h * HD + nt * 16 + c] = f2bf(oacc[nt][r]);
                }
            }
            __syncthreads();   // protects Pb/Vt for next head, qkvs for next pass
        }
    }

    // ---------- output projection: [49x192] @ [192x192]^T ----------
    short8 aof[4][6];
    #pragma unroll
    for (int mt = 0; mt < 4; ++mt) {
        int row = mt * 16 + c;
        #pragma unroll
        for (int ks = 0; ks < 6; ++ks)
            aof[mt][ks] = *(const short8*)&reg0[row * XS_S + ks * 32 + quad * 8];
    }
    for (int nt = w; nt < 12; nt += 4) {
        int j = nt * 16 + c;
        const ushort_t* bp = proj_wb + j * CDIM + quad * 8;
        floatx4 z = {0.f, 0.f, 0.f, 0.f};
        floatx4 acc[4];
        #pragma unroll
        for (int mt = 0; mt < 4; ++mt) acc[mt] = z;
        #pragma unroll
        for (int ks = 0; ks < 6; ++ks) {
            short8 bf = *(const short8*)(bp + ks * 32);
            #pragma unroll
            for (int mt = 0; mt < 4; ++mt)
                acc[mt] = __builtin_amdgcn_mfma_f32_16x16x32_bf16(
                    aof[mt][ks], bf, acc[mt], 0, 0, 0);
        }
        float pb = proj_b[j];
        #pragma unroll
        for (int mt = 0; mt < 4; ++mt) {
            #pragma unroll
            for (int r = 0; r < 4; ++r) {
                int n = mt * 16 + quad * 4 + r;
                if (n < NTOK)
                    out[((size_t)b * NTOK + n) * CDIM + j] = acc[mt][r] + pb;
            }
        }
    }
}

extern "C" void kernel_launch(void* const* d_in, const int* in_sizes, int n_in,
                              void* d_out, int out_size, void* d_ws, size_t ws_size,
                              hipStream_t stream)
{
    const float* x      = (const float*)d_in[0];
    const float* qkv_w  = (const float*)d_in[1];
    const float* qkv_b  = (const float*)d_in[2];
    const float* proj_w = (const float*)d_in[3];
    const float* proj_b = (const float*)d_in[4];
    const float* rpe_t  = (const float*)d_in[5];
    const int*   rpe_i  = (const int*)d_in[6];
    float*       o      = (float*)d_out;

    // workspace layout: qkv_w bf16 (221184 B) | proj_w bf16 (73728 B) | bias fp32 (75264 B)
    ushort_t* qkv_wb  = (ushort_t*)d_ws;
    ushort_t* proj_wb = qkv_wb + 110592;
    float*    biasws  = (float*)((char*)d_ws + (110592 + 36864) * sizeof(ushort_t));

    int tot = 147456 + NH * NTOK * 64;
    wmsa_prologue<<<dim3((tot + 255) / 256), dim3(256), 0, stream>>>(
        qkv_w, proj_w, rpe_t, rpe_i, qkv_wb, proj_wb, biasws);
    wmsa_mfma<<<dim3(NWIN), dim3(256), 0, stream>>>(
        x, qkv_wb, qkv_b, proj_wb, proj_b, biasws, o);
}